// Round 8
// baseline (205.147 us; speedup 1.0000x reference)
//
#include <hip/hip_runtime.h>
#include <hip/hip_bf16.h>

// MHA flash-attention fwd, fp32 in/out, f16 MFMA internals, fp32 accum.
// B=4, S=1024, D=2048, H=16, hd=128, causal.
// R14: 2-WAVE BLOCKS (128 thr), q-tile 32, k-tile 32, 16KB LDS, 2048 blocks.
//      R13 refuted the chain-length model (8-iter chains, 1536 blocks -> no
//      change); wall is ~5.4k cyc per 64-key iter per CU with every pipe
//      <45% and achieved residency stuck at a fraction of static. The one
//      never-varied axis is waves-per-block: if the effective-stream cap is
//      tied to block granularity (barrier scope / co-allocation), many
//      2-wave blocks raise achieved waves where more 4-wave blocks could
//      not. Also halves K/V-fragment read redundancy (2 waves share each
//      staged tile, not 4). Per-unit work otherwise identical to R7.
//      Inner loop = R7 exactly (2-barrier, XOR swizzles, S^T trick,
//      prefetch-1-tile, pack deferred past barrier, static-max softmax).
//      Diagonal tile: wave-uniform dead/masked st-cases skip dead MFMAs.

#define HEADS  16
#define HD     128
#define SEQ    1024
#define DMODEL 2048

typedef _Float16 f16;
typedef __attribute__((ext_vector_type(8))) _Float16 f16x8;
typedef __attribute__((ext_vector_type(4))) _Float16 f16x4;
typedef __attribute__((ext_vector_type(4))) float    f32x4;
typedef __attribute__((ext_vector_type(4))) unsigned int u32x4;

__device__ __forceinline__ unsigned int pkrtz(float a, float b) {
    return __builtin_bit_cast(unsigned int, __builtin_amdgcn_cvt_pkrtz(a, b));
}

__global__ __launch_bounds__(128, 2)
void fa_fwd(const float* __restrict__ Q,
            const float* __restrict__ K,
            const float* __restrict__ V,
            float* __restrict__ O)
{
    __shared__ f16 kT[32 * 128];   // K tile [key][d], 16B-granule swizzle g^(key&15)  (8KB)
    __shared__ f16 vT[128 * 32];   // V^T  [d][key], 8B-slot swizzle s^(d&7)           (8KB)

    const int tid  = threadIdx.x;  // 0..127
    const int lane = tid & 63;
    const int wv   = tid >> 6;     // 0..1
    const int quad = lane >> 4;
    const int cl   = lane & 15;

    const int bh = blockIdx.x;            // head; linear id % 8 pattern keeps head XCD-local
    const int qt = 31 - blockIdx.y;       // longest-first
    const int qb = qt * 32;
    const long long head_off = ((long long)(bh >> 4) * SEQ) * DMODEL
                             + (long long)(bh & 15) * HD;
    const float rscale = 0.08838834764831845f;   // 1/sqrt(128)

    // K staging: thread covers rows krow+8i (i=0..3), granule kg (8 f16)
    const int krow = tid >> 4;            // 0..7
    const int kg   = tid & 15;
    // V staging: thread covers keys vr0,vr0+1 x d = vcg*16+j (j=0..15)
    const int vr0  = (tid & 15) * 2;      // even keys 0..30
    const int vcg  = tid >> 4;            // 0..7
    const int vslot = vr0 >> 2;           // 8B-slot (4 keys each)
    const int vsub  = (vr0 & 3) >> 1;     // u32 within slot

    f32x4 kraw[8], vraw[8];

    auto loadKV = [&](int kbase) {
        #pragma unroll
        for (int i = 0; i < 4; ++i) {
            const float* kp = K + head_off + (long long)(kbase + krow + 8 * i) * DMODEL + kg * 8;
            kraw[2 * i]     = *(const f32x4*)kp;
            kraw[2 * i + 1] = *(const f32x4*)(kp + 4);
        }
        const float* vp = V + head_off + (long long)(kbase + vr0) * DMODEL + vcg * 16;
        #pragma unroll
        for (int j = 0; j < 4; ++j) {
            vraw[j]     = *(const f32x4*)(vp + 4 * j);
            vraw[4 + j] = *(const f32x4*)(vp + DMODEL + 4 * j);
        }
    };

    // ---- Q fragments (row = qb + wv*16 + cl, k = quad*8 + j per kk) ----
    const int qrow = qb + wv * 16 + cl;
    f16x8 qf[4];
    {
        const float* qp = Q + head_off + (long long)qrow * DMODEL + quad * 8;
        #pragma unroll
        for (int kk = 0; kk < 4; ++kk) {
            f32x4 qa = *(const f32x4*)(qp + kk * 32);
            f32x4 qc = *(const f32x4*)(qp + kk * 32 + 4);
            union { f16x8 v; unsigned int u[4]; } qw;
            qw.u[0] = pkrtz(qa[0], qa[1]);
            qw.u[1] = pkrtz(qa[2], qa[3]);
            qw.u[2] = pkrtz(qc[0], qc[1]);
            qw.u[3] = pkrtz(qc[2], qc[3]);
            qf[kk] = qw.v;
        }
    }

    f32x4 acc[8];    // O^T: row d = dt*16 + quad*4 + r, col qrow = cl
    #pragma unroll
    for (int i = 0; i < 8; ++i) acc[i] = (f32x4){0.f, 0.f, 0.f, 0.f};
    float ls = 0.f;

    loadKV(0);

    #pragma unroll 1
    for (int kt = 0; kt <= qt; ++kt) {
        __syncthreads();   // prior iter's LDS reads complete

        // ---- pack (loads issued an iteration ago) + stage ----
        #pragma unroll
        for (int i = 0; i < 4; ++i) {
            const int row = krow + 8 * i;
            u32x4 w;
            w.x = pkrtz(kraw[2 * i][0], kraw[2 * i][1]);
            w.y = pkrtz(kraw[2 * i][2], kraw[2 * i][3]);
            w.z = pkrtz(kraw[2 * i + 1][0], kraw[2 * i + 1][1]);
            w.w = pkrtz(kraw[2 * i + 1][2], kraw[2 * i + 1][3]);
            *(u32x4*)&kT[row * 128 + (kg ^ (row & 15)) * 8] = w;
        }
        #pragma unroll
        for (int j = 0; j < 16; ++j) {
            const int d = vcg * 16 + j;
            unsigned int pk = pkrtz(vraw[j >> 2][j & 3], vraw[4 + (j >> 2)][j & 3]);
            ((unsigned int*)vT)[d * 16 + (vslot ^ (d & 7)) * 2 + vsub] = pk;
        }
        __syncthreads();

        if (kt < qt) loadKV((kt + 1) * 32);   // in flight across GEMM1+exp+GEMM2+barrier

        const bool diag  = (kt == qt);
        const bool dead1 = diag && (wv == 0);   // st=1 fully masked for wave 0 on diagonal

        // ---- S^T = K Q^T : C[key = st*16+quad*4+r][qrow = cl] ----
        f32x4 sc[2];
        sc[0] = (f32x4){0.f, 0.f, 0.f, 0.f};
        sc[1] = (f32x4){0.f, 0.f, 0.f, 0.f};
        #pragma unroll
        for (int kk = 0; kk < 4; ++kk) {
            f16x8 kf0 = *(const f16x8*)&kT[(cl) * 128 + ((kk * 4 + quad) ^ cl) * 8];
            sc[0] = __builtin_amdgcn_mfma_f32_16x16x32_f16(kf0, qf[kk], sc[0], 0, 0, 0);
            if (!dead1) {
                f16x8 kf1 = *(const f16x8*)&kT[(16 + cl) * 128 + ((kk * 4 + quad) ^ cl) * 8];
                sc[1] = __builtin_amdgcn_mfma_f32_16x16x32_f16(kf1, qf[kk], sc[1], 0, 0, 0);
            }
        }

        // ---- exp (static-max softmax) -> P^T directly in B-frag layout ----
        const int kbase = kt * 32;
        f16x4 pf[2];
        {   // st = 0: masked iff diagonal && wv==0
            float e[4];
            #pragma unroll
            for (int r = 0; r < 4; ++r) {
                float ex = __expf(sc[0][r] * rscale);
                if (diag && wv == 0) {
                    int key = kbase + quad * 4 + r;
                    ex = (key <= qrow) ? ex : 0.f;
                }
                e[r] = ex;
                ls += e[r];
            }
            union { f16x4 v; unsigned int u[2]; } pw;
            pw.u[0] = pkrtz(e[0], e[1]);
            pw.u[1] = pkrtz(e[2], e[3]);
            pf[0] = pw.v;
        }
        if (!dead1) {   // st = 1: masked iff diagonal && wv==1
            float e[4];
            #pragma unroll
            for (int r = 0; r < 4; ++r) {
                float ex = __expf(sc[1][r] * rscale);
                if (diag && wv == 1) {
                    int key = kbase + 16 + quad * 4 + r;
                    ex = (key <= qrow) ? ex : 0.f;
                }
                e[r] = ex;
                ls += e[r];
            }
            union { f16x4 v; unsigned int u[2]; } pw;
            pw.u[0] = pkrtz(e[0], e[1]);
            pw.u[1] = pkrtz(e[2], e[3]);
            pf[1] = pw.v;
        }

        // ---- O^T += V^T P^T (A = V^T from LDS, B = P^T in regs) ----
        #pragma unroll
        for (int dt = 0; dt < 8; ++dt) {
            f16x4 vf0 = *(const f16x4*)&vT[(dt * 16 + cl) * 32
                                           + ((quad) ^ (cl & 7)) * 4];
            acc[dt] = __builtin_amdgcn_mfma_f32_16x16x16f16(vf0, pf[0], acc[dt], 0, 0, 0);
            if (!dead1) {
                f16x4 vf1 = *(const f16x4*)&vT[(dt * 16 + cl) * 32
                                               + ((4 + quad) ^ (cl & 7)) * 4];
                acc[dt] = __builtin_amdgcn_mfma_f32_16x16x16f16(vf1, pf[1], acc[dt], 0, 0, 0);
            }
        }
    }

    // ---- epilogue: reduce denom over quads, normalize, store f32x4 ----
    float lsum = ls;
    lsum += __shfl_xor(lsum, 16, 64);
    lsum += __shfl_xor(lsum, 32, 64);
    const float rl = 1.0f / lsum;

    float* op = O + head_off + (long long)qrow * DMODEL + quad * 4;
    #pragma unroll
    for (int dt = 0; dt < 8; ++dt) {
        f32x4 o4 = acc[dt];
        o4[0] *= rl; o4[1] *= rl; o4[2] *= rl; o4[3] *= rl;
        *(f32x4*)(op + dt * 16) = o4;
    }
}

extern "C" void kernel_launch(void* const* d_in, const int* in_sizes, int n_in,
                              void* d_out, int out_size, void* d_ws, size_t ws_size,
                              hipStream_t stream) {
    const float* q = (const float*)d_in[0];
    const float* k = (const float*)d_in[1];
    const float* v = (const float*)d_in[2];
    float* o = (float*)d_out;

    dim3 grid(4 * HEADS, SEQ / 32);   // x = head (XCD-local), y = q-tile (rev, longest-first)
    dim3 block(128);                  // 2 waves
    fa_fwd<<<grid, block, 0, stream>>>(q, k, v, o);
}

// Round 9
// 174.211 us; speedup vs baseline: 1.1776x; 1.1776x over previous
//
#include <hip/hip_runtime.h>
#include <hip/hip_bf16.h>

// MHA flash-attention fwd, fp32 in/out, f16 MFMA internals, fp32 accum.
// B=4, S=1024, D=2048, H=16, hd=128, causal.
// R15: PRE-PASS f16 IMAGE + global_load_lds DMA staging.
//      R7-R14 exhausted the concurrency axis: achieved waves/CU is pinned
//      at ~8 for every grid/block/split shape, wall = block-iters x ~5.4k
//      cyc, all pipes <50%. So attack per-iteration WORK: prep_kv converts
//      K,V once into a 32MB f16 image whose byte order IS the swizzled LDS
//      tile layout (pre-swizzled-global pattern); fa_fwd stages tiles with
//      global_load_lds (16B/lane, wave-uniform LDS base + lane*16 matches
//      the image order), double-buffered, ONE __syncthreads per iter (its
//      implicit vmcnt drain == "tile landed"). Deletes from the loop: all
//      pkrtz unpack, all ds_writes, the vmcnt-gated unpack chain, and 64
//      staging VGPRs. Loads for kt+1 fly across GEMM1+exp+GEMM2 of kt.
//      GEMM indexing/swizzles/S^T-trick/static-max softmax = R7 verbatim.

#define HEADS  16
#define HD     128
#define SEQ    1024
#define DMODEL 2048
#define IMG_CHUNK 32768   // 16KB kT + 16KB vT per (head, 64-key tile)

typedef _Float16 f16;
typedef __attribute__((ext_vector_type(8))) _Float16 f16x8;
typedef __attribute__((ext_vector_type(4))) _Float16 f16x4;
typedef __attribute__((ext_vector_type(4))) float    f32x4;
typedef __attribute__((ext_vector_type(4))) unsigned int u32x4;

typedef __attribute__((address_space(1))) const unsigned char gl_u8;
typedef __attribute__((address_space(3))) unsigned char lds_u8;

__device__ unsigned char KVIMG[64ull * 16ull * IMG_CHUNK];   // 32 MB static

__device__ __forceinline__ unsigned int pkrtz(float a, float b) {
    return __builtin_bit_cast(unsigned int, __builtin_amdgcn_cvt_pkrtz(a, b));
}

__device__ __forceinline__ void dma16(const void* g, void* l) {
    __builtin_amdgcn_global_load_lds((gl_u8*)g, (lds_u8*)l, 16, 0, 0);
}

// ---- pre-pass: build pre-swizzled f16 K/V image (byte order == LDS tiles) ----
__global__ __launch_bounds__(256, 2)
void prep_kv(const float* __restrict__ K, const float* __restrict__ V)
{
    __shared__ f16 kL[64 * 128];   // kT tile image: [key][d] g^(key&15) granule swizzle
    __shared__ f16 vL[128 * 64];   // vT tile image: [d][key] slot swizzle s^(d&7)

    const int tid = threadIdx.x;
    const int bh  = blockIdx.x;    // batch*16 + head
    const int kb  = blockIdx.y;    // 64-key tile index
    const long long head_off = ((long long)(bh >> 4) * SEQ) * DMODEL
                             + (long long)(bh & 15) * HD;
    const int kbase = kb * 64;

    // K staging geometry (R7): rows krow+16i, granule kg, swizzled kg^krow
    const int krow = tid >> 4;
    const int kg   = tid & 15;
    const int kgs  = kg ^ krow;
    #pragma unroll
    for (int i = 0; i < 4; ++i) {
        const float* kp = K + head_off + (long long)(kbase + krow + 16 * i) * DMODEL + kg * 8;
        f32x4 a = *(const f32x4*)kp;
        f32x4 b = *(const f32x4*)(kp + 4);
        u32x4 w;
        w.x = pkrtz(a[0], a[1]); w.y = pkrtz(a[2], a[3]);
        w.z = pkrtz(b[0], b[1]); w.w = pkrtz(b[2], b[3]);
        *(u32x4*)&kL[(krow + 16 * i) * 128 + kgs * 8] = w;
    }
    // V staging geometry (R7): keys vr0,vr0+1 x d = vcg*16+j
    const int vr0 = (tid & 31) * 2;
    const int vcg = tid >> 5;
    const int vg  = vr0 >> 3;
    const int vo  = vr0 & 7;
    {
        const float* vp = V + head_off + (long long)(kbase + vr0) * DMODEL + vcg * 16;
        f32x4 va[4], vb[4];
        #pragma unroll
        for (int j = 0; j < 4; ++j) {
            va[j] = *(const f32x4*)(vp + 4 * j);
            vb[j] = *(const f32x4*)(vp + DMODEL + 4 * j);
        }
        #pragma unroll
        for (int j = 0; j < 16; ++j) {
            unsigned int pk = pkrtz(va[j >> 2][j & 3], vb[j >> 2][j & 3]);
            *(unsigned int*)&vL[(vcg * 16 + j) * 64 + ((vg ^ (j & 7)) * 8) + vo] = pk;
        }
    }
    __syncthreads();

    // linear dump: image chunk = 16KB kT bytes then 16KB vT bytes
    unsigned char* dst = KVIMG + ((long long)(bh * 16 + kb)) * IMG_CHUNK;
    const unsigned char* ks = (const unsigned char*)kL;
    const unsigned char* vs = (const unsigned char*)vL;
    #pragma unroll
    for (int i = 0; i < 4; ++i) {
        *(u32x4*)(dst + tid * 16 + i * 4096)         = *(const u32x4*)(ks + tid * 16 + i * 4096);
        *(u32x4*)(dst + 16384 + tid * 16 + i * 4096) = *(const u32x4*)(vs + tid * 16 + i * 4096);
    }
}

// ---- main kernel: DMA-staged double-buffered flash attention ----
__global__ __launch_bounds__(256, 2)
void fa_fwd(const float* __restrict__ Q, float* __restrict__ O)
{
    __shared__ f16 kT[2][64 * 128];   // 32 KB
    __shared__ f16 vT[2][128 * 64];   // 32 KB

    const int tid  = threadIdx.x;
    const int lane = tid & 63;
    const int wv   = tid >> 6;
    const int quad = lane >> 4;
    const int cl   = lane & 15;

    const int bh = blockIdx.x;            // head; y-neighbors land on same XCD (64%8==0)
    const int qt = 15 - blockIdx.y;       // longest-first
    const int qb = qt * 64;
    const long long head_off = ((long long)(bh >> 4) * SEQ) * DMODEL
                             + (long long)(bh & 15) * HD;
    const float rscale = 0.08838834764831845f;   // 1/sqrt(128)

    const unsigned char* img = KVIMG + (long long)bh * 16 * IMG_CHUNK;

    // each wave DMAs its quarter of kT and vT: 4+4 x (64 lanes x 16B = 1KB)
    auto issueTile = [&](int buf, int kt) {
        const unsigned char* src = img + (long long)kt * IMG_CHUNK + wv * 4096 + lane * 16;
        unsigned char* kb = (unsigned char*)&kT[buf][0] + wv * 4096;
        unsigned char* vb = (unsigned char*)&vT[buf][0] + wv * 4096;
        #pragma unroll
        for (int i = 0; i < 4; ++i) dma16(src + i * 1024,          kb + i * 1024);
        #pragma unroll
        for (int i = 0; i < 4; ++i) dma16(src + 16384 + i * 1024,  vb + i * 1024);
    };

    // ---- Q fragments (row = qb + wv*16 + cl, k = quad*8 + j per kk) ----
    const int qrow = qb + wv * 16 + cl;
    f16x8 qf[4];
    {
        const float* qp = Q + head_off + (long long)qrow * DMODEL + quad * 8;
        #pragma unroll
        for (int kk = 0; kk < 4; ++kk) {
            f32x4 qa = *(const f32x4*)(qp + kk * 32);
            f32x4 qc = *(const f32x4*)(qp + kk * 32 + 4);
            union { f16x8 v; unsigned int u[4]; } qw;
            qw.u[0] = pkrtz(qa[0], qa[1]);
            qw.u[1] = pkrtz(qa[2], qa[3]);
            qw.u[2] = pkrtz(qc[0], qc[1]);
            qw.u[3] = pkrtz(qc[2], qc[3]);
            qf[kk] = qw.v;
        }
    }

    f32x4 acc[8];    // O^T: row d = dt*16 + quad*4 + r, col qrow = cl
    #pragma unroll
    for (int i = 0; i < 8; ++i) acc[i] = (f32x4){0.f, 0.f, 0.f, 0.f};
    float ls = 0.f;

    issueTile(0, 0);

    #pragma unroll 1
    for (int kt = 0; kt <= qt; ++kt) {
        const int c = kt & 1;

        // implicit vmcnt(0)+lgkmcnt(0) drain before s_barrier:
        // == "my DMA for tile kt landed" for every wave, and all buf c^1
        // reads from iter kt-1 are complete -> safe to overwrite it.
        __syncthreads();

        if (kt < qt) issueTile(c ^ 1, kt + 1);   // in flight across GEMM1+exp+GEMM2

        // ---- S^T = K Q^T : C[key = st*16+quad*4+r][qrow = cl] ----
        f32x4 sc[4];
        #pragma unroll
        for (int st = 0; st < 4; ++st) sc[st] = (f32x4){0.f, 0.f, 0.f, 0.f};
        __builtin_amdgcn_s_setprio(1);
        #pragma unroll
        for (int kk = 0; kk < 4; ++kk) {
            #pragma unroll
            for (int st = 0; st < 4; ++st) {
                f16x8 kf = *(const f16x8*)&kT[c][(st * 16 + cl) * 128
                                               + ((kk * 4 + quad) ^ cl) * 8];
                sc[st] = __builtin_amdgcn_mfma_f32_16x16x32_f16(kf, qf[kk], sc[st], 0, 0, 0);
            }
        }
        __builtin_amdgcn_s_setprio(0);

        // ---- exp (static-max softmax) -> P^T directly in B-frag layout ----
        const int kbase = kt * 64;
        f16x4 pf[4];
        if (kt == qt) {                // diagonal tile: causal mask
            #pragma unroll
            for (int st = 0; st < 4; ++st) {
                float e[4];
                #pragma unroll
                for (int r = 0; r < 4; ++r) {
                    int key = kbase + st * 16 + quad * 4 + r;
                    float ex = __expf(sc[st][r] * rscale);
                    e[r] = (key <= qrow) ? ex : 0.f;
                    ls += e[r];
                }
                union { f16x4 v; unsigned int u[2]; } pw;
                pw.u[0] = pkrtz(e[0], e[1]);
                pw.u[1] = pkrtz(e[2], e[3]);
                pf[st] = pw.v;
            }
        } else {
            #pragma unroll
            for (int st = 0; st < 4; ++st) {
                float e[4];
                #pragma unroll
                for (int r = 0; r < 4; ++r) {
                    e[r] = __expf(sc[st][r] * rscale);
                    ls += e[r];
                }
                union { f16x4 v; unsigned int u[2]; } pw;
                pw.u[0] = pkrtz(e[0], e[1]);
                pw.u[1] = pkrtz(e[2], e[3]);
                pf[st] = pw.v;
            }
        }

        // ---- O^T += V^T P^T (x32 MFMAs; A = V^T from LDS, B = P^T in regs) ----
        __builtin_amdgcn_s_setprio(1);
        #pragma unroll
        for (int dt = 0; dt < 8; ++dt) {
            #pragma unroll
            for (int st = 0; st < 4; ++st) {
                f16x4 vf = *(const f16x4*)&vT[c][(dt * 16 + cl) * 64
                                                + ((st * 2 + (quad >> 1)) ^ (cl & 7)) * 8
                                                + (quad & 1) * 4];
                acc[dt] = __builtin_amdgcn_mfma_f32_16x16x16f16(vf, pf[st], acc[dt], 0, 0, 0);
            }
        }
        __builtin_amdgcn_s_setprio(0);
    }

    // ---- epilogue: reduce denom over quads, normalize, store f32x4 ----
    float lsum = ls;
    lsum += __shfl_xor(lsum, 16, 64);
    lsum += __shfl_xor(lsum, 32, 64);
    const float rl = 1.0f / lsum;

    float* op = O + head_off + (long long)qrow * DMODEL + quad * 4;
    #pragma unroll
    for (int dt = 0; dt < 8; ++dt) {
        f32x4 o4 = acc[dt];
        o4[0] *= rl; o4[1] *= rl; o4[2] *= rl; o4[3] *= rl;
        *(f32x4*)(op + dt * 16) = o4;
    }
}

extern "C" void kernel_launch(void* const* d_in, const int* in_sizes, int n_in,
                              void* d_out, int out_size, void* d_ws, size_t ws_size,
                              hipStream_t stream) {
    const float* q = (const float*)d_in[0];
    const float* k = (const float*)d_in[1];
    const float* v = (const float*)d_in[2];
    float* o = (float*)d_out;

    prep_kv<<<dim3(64, 16), dim3(256), 0, stream>>>(k, v);
    fa_fwd <<<dim3(64, 16), dim3(256), 0, stream>>>(q, o);
}

// Round 10
// 171.728 us; speedup vs baseline: 1.1946x; 1.0145x over previous
//
#include <hip/hip_runtime.h>
#include <hip/hip_bf16.h>

// MHA flash-attention fwd, fp32 in/out, f16 MFMA internals, fp32 accum.
// B=4, S=1024, D=2048, H=16, hd=128, causal.
// R16: (a) prep_kv writes the pre-swizzled f16 image DIRECTLY from registers
//      (no LDS round-trip/barrier; swizzle permutes within 256B/128B
//      segments so stores stay coalesced): ~30us -> ~15us.
//      (b) fa_fwd: SINGLE-buffered kT and vT (32KB LDS -> 4 resident
//      blocks/CU, grid-pool cap). R15 proved per-iter work cut works
//      (76.7->51.4us) but ran at 2-block residency; since __syncthreads
//      drains vmcnt(0) at EVERY barrier, double-buffering never bought a
//      longer prefetch window anyway. Schedule: barrierA (K[kt] landed,
//      vT free) -> issue V[kt] DMA -> GEMM1+exp (covers V latency) ->
//      barrierB (V[kt] landed, kT free) -> issue K[kt+1] DMA -> GEMM2
//      (covers K latency). 2 barriers/iter (proven neutral R7 vs R10).
//      launch_bounds(256,4): VGPR cap 128 >> ~90 needed, no spill risk.
//      GEMM indexing/swizzles/S^T-trick/static-max softmax = R7 verbatim.

#define HEADS  16
#define HD     128
#define SEQ    1024
#define DMODEL 2048
#define IMG_CHUNK 32768   // 16KB kT + 16KB vT per (head, 64-key tile)

typedef _Float16 f16;
typedef __attribute__((ext_vector_type(8))) _Float16 f16x8;
typedef __attribute__((ext_vector_type(4))) _Float16 f16x4;
typedef __attribute__((ext_vector_type(4))) float    f32x4;
typedef __attribute__((ext_vector_type(4))) unsigned int u32x4;

typedef __attribute__((address_space(1))) const unsigned char gl_u8;
typedef __attribute__((address_space(3))) unsigned char lds_u8;

__device__ unsigned char KVIMG[64ull * 16ull * IMG_CHUNK];   // 32 MB static

__device__ __forceinline__ unsigned int pkrtz(float a, float b) {
    return __builtin_bit_cast(unsigned int, __builtin_amdgcn_cvt_pkrtz(a, b));
}

__device__ __forceinline__ void dma16(const void* g, void* l) {
    __builtin_amdgcn_global_load_lds((gl_u8*)g, (lds_u8*)l, 16, 0, 0);
}

// ---- pre-pass: build pre-swizzled f16 K/V image, registers -> global ----
__global__ __launch_bounds__(256)
void prep_kv(const float* __restrict__ K, const float* __restrict__ V)
{
    const int tid = threadIdx.x;
    const int bh  = blockIdx.x;    // batch*16 + head
    const int kb  = blockIdx.y;    // 64-key tile index
    const long long head_off = ((long long)(bh >> 4) * SEQ) * DMODEL
                             + (long long)(bh & 15) * HD;
    const int kbase = kb * 64;
    unsigned char* dst = KVIMG + ((long long)(bh * 16 + kb)) * IMG_CHUNK;

    // K: rows krow+16i, granule kg, swizzled granule kg^krow ((row&15)==krow)
    const int krow = tid >> 4;
    const int kg   = tid & 15;
    const int kgs  = kg ^ krow;
    #pragma unroll
    for (int i = 0; i < 4; ++i) {
        const int row = krow + 16 * i;
        const float* kp = K + head_off + (long long)(kbase + row) * DMODEL + kg * 8;
        f32x4 a = *(const f32x4*)kp;
        f32x4 b = *(const f32x4*)(kp + 4);
        u32x4 w;
        w.x = pkrtz(a[0], a[1]); w.y = pkrtz(a[2], a[3]);
        w.z = pkrtz(b[0], b[1]); w.w = pkrtz(b[2], b[3]);
        *(u32x4*)(dst + row * 256 + kgs * 16) = w;   // coalesced within row segment
    }
    // V: keys vr0,vr0+1 x d = vcg*16+j; vT f16-index (d*64 + (vg^(j&7))*8 + vo)
    const int vr0 = (tid & 31) * 2;
    const int vcg = tid >> 5;
    const int vg  = vr0 >> 3;
    const int vo  = vr0 & 7;
    {
        const float* vp = V + head_off + (long long)(kbase + vr0) * DMODEL + vcg * 16;
        f32x4 va[4], vb[4];
        #pragma unroll
        for (int j = 0; j < 4; ++j) {
            va[j] = *(const f32x4*)(vp + 4 * j);
            vb[j] = *(const f32x4*)(vp + DMODEL + 4 * j);
        }
        #pragma unroll
        for (int j = 0; j < 16; ++j) {
            const int d = vcg * 16 + j;
            unsigned int pk = pkrtz(va[j >> 2][j & 3], vb[j >> 2][j & 3]);
            *(unsigned int*)(dst + 16384 + (d * 64 + ((vg ^ (j & 7)) * 8) + vo) * 2) = pk;
        }
    }
}

// ---- main kernel: DMA-staged, single-buffered K and V, alternating barriers ----
__global__ __launch_bounds__(256, 4)
void fa_fwd(const float* __restrict__ Q, float* __restrict__ O)
{
    __shared__ f16 kT[64 * 128];   // 16 KB, K tile kt
    __shared__ f16 vT[128 * 64];   // 16 KB, V^T tile kt

    const int tid  = threadIdx.x;
    const int lane = tid & 63;
    const int wv   = tid >> 6;
    const int quad = lane >> 4;
    const int cl   = lane & 15;

    const int bh = blockIdx.x;            // head
    const int qt = 15 - blockIdx.y;       // longest-first
    const int qb = qt * 64;
    const long long head_off = ((long long)(bh >> 4) * SEQ) * DMODEL
                             + (long long)(bh & 15) * HD;
    const float rscale = 0.08838834764831845f;   // 1/sqrt(128)

    const unsigned char* img = KVIMG + (long long)bh * 16 * IMG_CHUNK;

    // each wave DMAs its quarter (4 x 1KB) of the 16KB half-chunk
    auto issueK = [&](int kt) {
        const unsigned char* src = img + (long long)kt * IMG_CHUNK + wv * 4096 + lane * 16;
        unsigned char* d = (unsigned char*)&kT[0] + wv * 4096;
        #pragma unroll
        for (int i = 0; i < 4; ++i) dma16(src + i * 1024, d + i * 1024);
    };
    auto issueV = [&](int kt) {
        const unsigned char* src = img + (long long)kt * IMG_CHUNK + 16384 + wv * 4096 + lane * 16;
        unsigned char* d = (unsigned char*)&vT[0] + wv * 4096;
        #pragma unroll
        for (int i = 0; i < 4; ++i) dma16(src + i * 1024, d + i * 1024);
    };

    // ---- Q fragments (row = qb + wv*16 + cl, k = quad*8 + j per kk) ----
    const int qrow = qb + wv * 16 + cl;
    f16x8 qf[4];
    {
        const float* qp = Q + head_off + (long long)qrow * DMODEL + quad * 8;
        #pragma unroll
        for (int kk = 0; kk < 4; ++kk) {
            f32x4 qa = *(const f32x4*)(qp + kk * 32);
            f32x4 qc = *(const f32x4*)(qp + kk * 32 + 4);
            union { f16x8 v; unsigned int u[4]; } qw;
            qw.u[0] = pkrtz(qa[0], qa[1]);
            qw.u[1] = pkrtz(qa[2], qa[3]);
            qw.u[2] = pkrtz(qc[0], qc[1]);
            qw.u[3] = pkrtz(qc[2], qc[3]);
            qf[kk] = qw.v;
        }
    }

    f32x4 acc[8];    // O^T: row d = dt*16 + quad*4 + r, col qrow = cl
    #pragma unroll
    for (int i = 0; i < 8; ++i) acc[i] = (f32x4){0.f, 0.f, 0.f, 0.f};
    float ls = 0.f;

    issueK(0);   // prologue: K[0] in flight; drained by barrierA of iter 0

    #pragma unroll 1
    for (int kt = 0; kt <= qt; ++kt) {
        // barrierA: per-wave vmcnt drain => K[kt] landed for every wave;
        // all waves finished GEMM2 reads of vT[kt-1] => vT free.
        __syncthreads();

        issueV(kt);   // lands during GEMM1+exp; published at barrierB

        // ---- S^T = K Q^T : C[key = st*16+quad*4+r][qrow = cl] ----
        f32x4 sc[4];
        #pragma unroll
        for (int st = 0; st < 4; ++st) sc[st] = (f32x4){0.f, 0.f, 0.f, 0.f};
        __builtin_amdgcn_s_setprio(1);
        #pragma unroll
        for (int kk = 0; kk < 4; ++kk) {
            #pragma unroll
            for (int st = 0; st < 4; ++st) {
                f16x8 kf = *(const f16x8*)&kT[(st * 16 + cl) * 128
                                              + ((kk * 4 + quad) ^ cl) * 8];
                sc[st] = __builtin_amdgcn_mfma_f32_16x16x32_f16(kf, qf[kk], sc[st], 0, 0, 0);
            }
        }
        __builtin_amdgcn_s_setprio(0);

        // ---- exp (static-max softmax) -> P^T directly in B-frag layout ----
        const int kbase = kt * 64;
        f16x4 pf[4];
        if (kt == qt) {                // diagonal tile: causal mask
            #pragma unroll
            for (int st = 0; st < 4; ++st) {
                float e[4];
                #pragma unroll
                for (int r = 0; r < 4; ++r) {
                    int key = kbase + st * 16 + quad * 4 + r;
                    float ex = __expf(sc[st][r] * rscale);
                    e[r] = (key <= qrow) ? ex : 0.f;
                    ls += e[r];
                }
                union { f16x4 v; unsigned int u[2]; } pw;
                pw.u[0] = pkrtz(e[0], e[1]);
                pw.u[1] = pkrtz(e[2], e[3]);
                pf[st] = pw.v;
            }
        } else {
            #pragma unroll
            for (int st = 0; st < 4; ++st) {
                float e[4];
                #pragma unroll
                for (int r = 0; r < 4; ++r) {
                    e[r] = __expf(sc[st][r] * rscale);
                    ls += e[r];
                }
                union { f16x4 v; unsigned int u[2]; } pw;
                pw.u[0] = pkrtz(e[0], e[1]);
                pw.u[1] = pkrtz(e[2], e[3]);
                pf[st] = pw.v;
            }
        }

        // barrierB: V[kt] landed for every wave; all waves done GEMM1 kT reads.
        __syncthreads();

        if (kt < qt) issueK(kt + 1);   // lands during GEMM2; published at next barrierA

        // ---- O^T += V^T P^T (x32 MFMAs; A = V^T from LDS, B = P^T in regs) ----
        __builtin_amdgcn_s_setprio(1);
        #pragma unroll
        for (int dt = 0; dt < 8; ++dt) {
            #pragma unroll
            for (int st = 0; st < 4; ++st) {
                f16x4 vf = *(const f16x4*)&vT[(dt * 16 + cl) * 64
                                              + ((st * 2 + (quad >> 1)) ^ (cl & 7)) * 8
                                              + (quad & 1) * 4];
                acc[dt] = __builtin_amdgcn_mfma_f32_16x16x16f16(vf, pf[st], acc[dt], 0, 0, 0);
            }
        }
        __builtin_amdgcn_s_setprio(0);
    }

    // ---- epilogue: reduce denom over quads, normalize, store f32x4 ----
    float lsum = ls;
    lsum += __shfl_xor(lsum, 16, 64);
    lsum += __shfl_xor(lsum, 32, 64);
    const float rl = 1.0f / lsum;

    float* op = O + head_off + (long long)qrow * DMODEL + quad * 4;
    #pragma unroll
    for (int dt = 0; dt < 8; ++dt) {
        f32x4 o4 = acc[dt];
        o4[0] *= rl; o4[1] *= rl; o4[2] *= rl; o4[3] *= rl;
        *(f32x4*)(op + dt * 16) = o4;
    }
}

extern "C" void kernel_launch(void* const* d_in, const int* in_sizes, int n_in,
                              void* d_out, int out_size, void* d_ws, size_t ws_size,
                              hipStream_t stream) {
    const float* q = (const float*)d_in[0];
    const float* k = (const float*)d_in[1];
    const float* v = (const float*)d_in[2];
    float* o = (float*)d_out;

    prep_kv<<<dim3(64, 16), dim3(256), 0, stream>>>(k, v);
    fa_fwd <<<dim3(64, 16), dim3(256), 0, stream>>>(q, o);
}